// Round 15
// baseline (11401.478 us; speedup 1.0000x reference)
//
#include <hip/hip_runtime.h>

#define H     512
#define BQ    64
#define TT    512
#define CIN   64
#define COUT  64
#define NWG   132           // 64 stage-A + 64 stage-B + 4 FC
#define THREADS 256
#define RSLOTS 32           // ring slots; address reuse period = 32 steps

typedef unsigned int  uint;
typedef unsigned short ushort;
typedef unsigned long long u64;
typedef short bf16x8 __attribute__((ext_vector_type(8)));
typedef float f32x4  __attribute__((ext_vector_type(4)));

// LDS layout (bytes): gate-interleaved weight pair-tiles, bf16 hi+lo
#define GH_BASE   0          // 2 tiles K=512 : 64 KB
#define GI_BASE   65536      // 2 tiles K<=512: 64 KB
#define GI0_BASE  131072     // 2 tiles K=64  :  8 KB  (dec-A t=0 only)
#define STG_BASE  139264     // ring-store staging: [64][8] hi + lo = 2 KB
#define SMEM_SIZE 141312

// ws layout (bytes)
#define WS_FLAGS  0          // 132 barrier flags, 64B apart: one writer per line
#define WS_FA     8448       // 64 dataflow flags (A-group step counters), 64B apart
#define WS_BAR_SZ 16384
#define WS_BP     16384      // b' f32[1536]
#define WS_F0H    22528      // f0 hi bf16[64][64] (flat row-major)
#define WS_F0L    30720
#define WS_H0RH   65536      // h0 ring [32 slots][64 kblk][64 row][8 col] bf16 hi : 2 MB
#define WS_H0RL   2162688
#define WS_H1RH   4259840
#define WS_H1RL   6356992
#define WS_M      8454144    // M f32[1536][512]

// slot offset in ushorts for absolute step s
#define SLOT(s)   (((s) & (RSLOTS-1)) * 32768)

struct Params {
  const float *x, *f0;
  const float *eWih0,*eWhh0,*ebih0,*ebhh0,*eWih1,*eWhh1,*ebih1,*ebhh1;
  const float *dWih0,*dWhh0,*dbih0,*dbhh0,*dWih1,*dWhh1,*dbih1,*dbhh1;
  const float *fcW,*fcb;
  float* out;
  char* ws;
};

__device__ __forceinline__ ushort f2bf(float v){
  uint b = __float_as_uint(v);
  return (ushort)((b + 0x7FFFu + ((b >> 16) & 1u)) >> 16);
}
__device__ __forceinline__ float bf2f(ushort u){ return __uint_as_float(((uint)u) << 16); }

// ---------------- grid barrier: R11/R14 exactly (validated best).
__device__ __forceinline__ void gbar(uint* flags, uint r, int wg, int tid, bool rel, bool inv){
  __syncthreads();                                   // ring stores drained (vmcnt 0)
  if (tid == 0){
    if (rel) __builtin_amdgcn_fence(__ATOMIC_RELEASE, "agent");   // flush plain-stored staging
    __hip_atomic_store(&flags[wg*16], r, __ATOMIC_RELAXED, __HIP_MEMORY_SCOPE_AGENT);
  }
  asm volatile("" ::: "memory");
  if (tid < NWG){
    uint it = 0;
    while (__hip_atomic_load(&flags[tid*16], __ATOMIC_RELAXED, __HIP_MEMORY_SCOPE_AGENT) < r){
      __builtin_amdgcn_s_sleep(1);
      if ((++it & 1023u) == 0u) __builtin_amdgcn_fence(__ATOMIC_ACQUIRE, "agent");  // parachute only
    }
  }
  __syncthreads();
  if (inv) __builtin_amdgcn_fence(__ATOMIC_ACQUIRE, "agent");     // periodic L1/L2 invalidate
}

// ---------------- dataflow wait on the 64 A-group flags (decoder mid-round
// handoff). One writer per 64B line; relaxed coherence-point polls, no
// in-loop fences (parachute only).
__device__ __forceinline__ void waitS(const uint* __restrict__ f, uint thr, int tid){
  if (tid < 64){
    uint it = 0;
    while (__hip_atomic_load(&f[tid*16], __ATOMIC_RELAXED, __HIP_MEMORY_SCOPE_AGENT) < thr){
      __builtin_amdgcn_s_sleep(1);
      if ((++it & 1023u) == 0u) __builtin_amdgcn_fence(__ATOMIC_ACQUIRE, "agent");
    }
  }
  __syncthreads();
}
__device__ __forceinline__ void publish(uint* f, uint v){
  __hip_atomic_store(f, v, __ATOMIC_RELAXED, __HIP_MEMORY_SCOPE_AGENT);
}

// ---------------- pack 2 gate-interleaved pair-tiles (32 slots x K) into LDS
template<int K>
__device__ void packW(char* lds, int base, const float* __restrict__ W, int colbase, int tid){
  for (int e = tid; e < 32*K; e += THREADS){
    int S = e / K, k = e - S*K;
    int gate = S & 3, hcl = S >> 2;
    float v = (gate < 3) ? W[(gate*H + colbase + hcl)*K + k] : 0.f;
    ushort hi = f2bf(v);
    ushort lo = f2bf(v - bf2f(hi));
    int tau = S >> 4, s = S & 15;
    int off = ((s*K + k)*2) ^ ((s & 7) << 4);
    char* tb = lds + base + tau*(16*K*4);
    *(ushort*)(tb + off) = hi;
    *(ushort*)(tb + 16*K*2 + off) = lo;
  }
}

__device__ void packFC(char* lds, const float* __restrict__ fcW, int colbase, int tid){
  for (int e = tid; e < 16*512; e += THREADS){
    int s = e >> 9, k = e & 511;
    float v = fcW[(colbase + s)*512 + k];
    ushort hi = f2bf(v);
    ushort lo = f2bf(v - bf2f(hi));
    int off = ((s*512 + k)*2) ^ ((s & 7) << 4);
    *(ushort*)(lds + off) = hi;
    *(ushort*)(lds + 16*512*2 + off) = lo;
  }
}

__device__ __forceinline__ void loadBias(const float* __restrict__ src, int colbase, int c, float* b){
#pragma unroll
  for (int tau = 0; tau < 2; ++tau){
    int gate = c & 3, hcl = 4*tau + (c >> 2);
    b[tau] = (gate < 3) ? src[gate*H + colbase + hcl] : 0.f;
  }
}

// blocked ring element (row, col): ushort offset (col>>3)*512 + row*8 + (col&7)
__device__ __forceinline__ void loadHold(const ushort* rh, const ushort* rl, int colb,
                                         int m, int lane, f32x4* hold){
  int c = lane & 15, g = lane >> 4;
#pragma unroll
  for (int tau = 0; tau < 2; ++tau){
    int col = colb + 4*tau + (c >> 2);
#pragma unroll
    for (int q = 0; q < 4; ++q){
      int row = m*16 + g*4 + q;
      int off = (col >> 3)*512 + row*8 + (col & 7);
      hold[tau][q] = bf2f(rh[off]) + bf2f(rl[off]);
    }
  }
}

// ---------------- 64xNTAU*16 GEMM tile, split-bf16 3-term, weights from LDS
// BLK=true: A in blocked ring layout [kblk][row][8]. BLK=false: flat [64][K].
template<int NTAU, int K, bool BLK>
__device__ __forceinline__ void gemm(const ushort* __restrict__ AH, const ushort* __restrict__ AL,
                                     const char* lds, int base, const float* bias,
                                     int m, int lane, f32x4* pre){
  const int c = lane & 15, g = lane >> 4;
  const int row = m*16 + c;
  constexpr int NK = K/32;
  bf16x8 ahv[NK], alv[NK];
#pragma unroll
  for (int kc = 0; kc < NK; ++kc){
    const int aoff = BLK ? ((kc*4 + g)*512 + row*8) : (row*K + kc*32 + g*8);
    ahv[kc] = *(const bf16x8*)(AH + aoff);
    alv[kc] = *(const bf16x8*)(AL + aoff);
  }
  f32x4 a1[NTAU], a2[NTAU];
#pragma unroll
  for (int tau = 0; tau < NTAU; ++tau){
    a1[tau] = f32x4{bias[tau], bias[tau], bias[tau], bias[tau]};
    a2[tau] = f32x4{0.f, 0.f, 0.f, 0.f};
  }
#pragma unroll
  for (int kc = 0; kc < NK; ++kc){
    const int off = ((c*K + kc*32 + g*8)*2) ^ ((c & 7) << 4);
#pragma unroll
    for (int tau = 0; tau < NTAU; ++tau){
      const char* tb = lds + base + tau*(16*K*4);
      bf16x8 wh = *(const bf16x8*)(tb + off);
      bf16x8 wl = *(const bf16x8*)(tb + 16*K*2 + off);
      a1[tau] = __builtin_amdgcn_mfma_f32_16x16x32_bf16(ahv[kc], wh, a1[tau], 0, 0, 0);
      a2[tau] = __builtin_amdgcn_mfma_f32_16x16x32_bf16(ahv[kc], wl, a2[tau], 0, 0, 0);
      a2[tau] = __builtin_amdgcn_mfma_f32_16x16x32_bf16(alv[kc], wh, a2[tau], 0, 0, 0);
    }
  }
#pragma unroll
  for (int tau = 0; tau < NTAU; ++tau) pre[tau] = a1[tau] + a2[tau];
}

// ---------------- GRU gates: compute hn, update hold, STAGE hi/lo tiles in LDS.
__device__ __forceinline__ void gates_stage(const f32x4* pgi, const f32x4* pgh, f32x4* hold,
                                            ushort* __restrict__ stH, ushort* __restrict__ stL,
                                            int m, int lane){
  const int c = lane & 15, g = lane >> 4;
#pragma unroll
  for (int tau = 0; tau < 2; ++tau){
    f32x4 s, n, hn, rsh, zsh;
#pragma unroll
    for (int q = 0; q < 4; ++q) s[q] = 1.f / (1.f + expf(-(pgi[tau][q] + pgh[tau][q])));
#pragma unroll
    for (int q = 0; q < 4; ++q) rsh[q] = __shfl_xor(s[q], 2, 64);
#pragma unroll
    for (int q = 0; q < 4; ++q) zsh[q] = __shfl_xor(s[q], 3, 64);
#pragma unroll
    for (int q = 0; q < 4; ++q) n[q] = tanhf(pgi[tau][q] + rsh[q]*pgh[tau][q]);
#pragma unroll
    for (int q = 0; q < 4; ++q) hn[q] = (1.f - zsh[q])*n[q] + zsh[q]*hold[tau][q];
    hold[tau] = hn;
    if ((c & 3) == 2){
      const int cl = 4*tau + (c >> 2);                // local col 0..7
#pragma unroll
      for (int q = 0; q < 4; ++q){
        const int row = m*16 + g*4 + q;
        ushort hi = f2bf(hn[q]);
        ushort lo = f2bf(hn[q] - bf2f(hi));
        stH[row*8 + cl] = hi;
        stL[row*8 + cl] = lo;
      }
    }
  }
}

// ---------------- flush staged [64][8] tiles as 32 FULL 64B lines per WG
__device__ __forceinline__ void ring_flush(ushort* __restrict__ dH, ushort* __restrict__ dL,
                                           const ushort* __restrict__ stH,
                                           const ushort* __restrict__ stL, int tid){
  if (tid < 128){
    u64 v = *(const u64*)(stH + tid*4);
    __hip_atomic_store((u64*)dH + tid, v, __ATOMIC_RELAXED, __HIP_MEMORY_SCOPE_AGENT);
  } else if (tid < 256){
    int t2 = tid - 128;
    u64 v = *(const u64*)(stL + t2*4);
    __hip_atomic_store((u64*)dL + t2, v, __ATOMIC_RELAXED, __HIP_MEMORY_SCOPE_AGENT);
  }
}

__device__ __forceinline__ f32x4 bc4(float v){ return f32x4{v, v, v, v}; }

__global__ __launch_bounds__(THREADS, 1) void rnn_persist(Params p){
  extern __shared__ char smem[];
  char* ws = p.ws;
  uint* flags = (uint*)(ws + WS_FLAGS);
  uint* fA    = (uint*)(ws + WS_FA);
  float*  bp   = (float*)(ws + WS_BP);
  ushort* f0H  = (ushort*)(ws + WS_F0H);
  ushort* f0L  = (ushort*)(ws + WS_F0L);
  ushort* h0rH = (ushort*)(ws + WS_H0RH);
  ushort* h0rL = (ushort*)(ws + WS_H0RL);
  ushort* h1rH = (ushort*)(ws + WS_H1RH);
  ushort* h1rL = (ushort*)(ws + WS_H1RL);
  float*  Mw   = (float*)(ws + WS_M);
  ushort* xTH  = (ushort*)(void*)p.out;              // staged in d_out; dead before FC writes
  ushort* xTL  = xTH + TT*BQ*CIN;
  ushort* stH  = (ushort*)(smem + STG_BASE);         // [64][8] staging
  ushort* stL  = stH + 512;

  const int wg = blockIdx.x, tid = threadIdx.x;
  const int wid = tid >> 6, lane = tid & 63;
  const int c = lane & 15;
  const int gtid = wg*THREADS + tid;
  const int gstride = NWG*THREADS;
  uint bno = 0;

  // ================= prepass: xT (transpose+split), f0, M = dWih0@fcW, b'
  for (int e = gtid; e < TT*BQ*CIN; e += gstride){
    int t = e >> 12, b = (e >> 6) & 63, cc = e & 63;
    float v = p.x[(b*CIN + cc)*TT + t];
    ushort hi = f2bf(v);
    xTH[e] = hi; xTL[e] = f2bf(v - bf2f(hi));
  }
  for (int e = gtid; e < BQ*COUT; e += gstride){
    float v = p.f0[e];
    ushort hi = f2bf(v);
    f0H[e] = hi; f0L[e] = f2bf(v - bf2f(hi));
  }
  {
    const int total = 1536*512;
    const int per = (total + gstride - 1) / gstride;
    const int start = gtid * per;
    for (int i = 0; i < per; ++i){
      int e = start + i;
      if (e >= total) break;
      int rr = e >> 9, q = e & 511;
      float acc = 0.f;
      for (int k = 0; k < 64; ++k) acc += p.dWih0[rr*64 + k] * p.fcW[k*512 + q];
      Mw[e] = acc;
    }
  }
  for (int e = gtid; e < 1536; e += gstride){
    float acc = p.dbih0[e];
    for (int k = 0; k < 64; ++k) acc += p.dWih0[e*64 + k] * p.fcb[k];
    bp[e] = acc;
  }
  gbar(flags, ++bno, wg, tid, true, true);   // release staging + start clean

  // ================= pack encoder weights into LDS, load biases
  const bool isA = (wg < 64), isB = (wg >= 64 && wg < 128);
  const int colb = isA ? wg*8 : (wg - 64)*8;
  const int kblk = colb >> 3;                         // this WG's ring column-block
  float bgi[2] = {0.f,0.f}, bgh[2] = {0.f,0.f}, bgi0[2] = {0.f,0.f}, bfc = 0.f;
  f32x4 hold[2]; hold[0] = bc4(0.f); hold[1] = bc4(0.f);
  int fccol = 0;
  if (isA){
    packW<64 >(smem, GI_BASE, p.eWih0, colb, tid);
    packW<512>(smem, GH_BASE, p.eWhh0, colb, tid);
    loadBias(p.ebih0, colb, c, bgi); loadBias(p.ebhh0, colb, c, bgh);
  } else if (isB){
    packW<512>(smem, GI_BASE, p.eWih1, colb, tid);
    packW<512>(smem, GH_BASE, p.eWhh1, colb, tid);
    loadBias(p.ebih1, colb, c, bgi); loadBias(p.ebhh1, colb, c, bgh);
  } else {
    fccol = (wg - 128)*16;
    packFC(smem, p.fcW, fccol, tid);
    bfc = p.fcb[fccol + c];
  }
  gbar(flags, ++bno, wg, tid, false, false);

  // ================= encoder: 513 pipelined rounds (A: L0 @ t=r ; B: L1 @ t=r-1)
  for (int r = 0; r <= TT; ++r){
    if (isA && r < TT){
      const int t = r;
      f32x4 pgi[2], pgh[2];
      if (t > 0)
        gemm<2,512,true>(h0rH + SLOT(t-1), h0rL + SLOT(t-1), smem, GH_BASE, bgh, wid, lane, pgh);
      else { pgh[0] = bc4(bgh[0]); pgh[1] = bc4(bgh[1]); }
      gemm<2,64,false>(xTH + t*4096, xTL + t*4096, smem, GI_BASE, bgi, wid, lane, pgi);
      gates_stage(pgi, pgh, hold, stH, stL, wid, lane);
      __syncthreads();
      ring_flush(h0rH + SLOT(t) + kblk*512, h0rL + SLOT(t) + kblk*512, stH, stL, tid);
    } else if (isB && r >= 1){
      const int t = r - 1;
      f32x4 pgi[2], pgh[2];
      if (t > 0)
        gemm<2,512,true>(h1rH + SLOT(t-1), h1rL + SLOT(t-1), smem, GH_BASE, bgh, wid, lane, pgh);
      else { pgh[0] = bc4(bgh[0]); pgh[1] = bc4(bgh[1]); }
      gemm<2,512,true>(h0rH + SLOT(t), h0rL + SLOT(t), smem, GI_BASE, bgi, wid, lane, pgi);
      gates_stage(pgi, pgh, hold, stH, stL, wid, lane);
      __syncthreads();
      ring_flush(h1rH + SLOT(t) + kblk*512, h1rL + SLOT(t) + kblk*512, stH, stL, tid);
    }
    ++bno;
    gbar(flags, bno, wg, tid, false, (bno & 15u) == 0u);
  }

  // ================= repack decoder weights, reload state (enc finals = step 511)
  if (isA){
    packW<512>(smem, GH_BASE, p.dWhh0, colb, tid);
    packW<512>(smem, GI_BASE, Mw,      colb, tid);   // folded FC->L0 input weights
    packW<64 >(smem, GI0_BASE, p.dWih0, colb, tid);
    loadBias(bp,      colb, c, bgi);
    loadBias(p.dbhh0, colb, c, bgh);
    loadBias(p.dbih0, colb, c, bgi0);
    loadHold(h0rH + SLOT(511), h0rL + SLOT(511), colb, wid, lane, hold);
  } else if (isB){
    packW<512>(smem, GI_BASE, p.dWih1, colb, tid);
    packW<512>(smem, GH_BASE, p.dWhh1, colb, tid);
    loadBias(p.dbih1, colb, c, bgi); loadBias(p.dbhh1, colb, c, bgh);
    loadHold(h1rH + SLOT(511), h1rL + SLOT(511), colb, wid, lane, hold);
  }
  gbar(flags, ++bno, wg, tid, false, true);          // phase transition: force inv

  // A: prefetch gh for step 512 (operand h0^511, slot 511 — post-inv fresh)
  f32x4 pgh_s[2]; pgh_s[0] = bc4(0.f); pgh_s[1] = bc4(0.f);
  if (isA)
    gemm<2,512,true>(h0rH + SLOT(511), h0rL + SLOT(511), smem, GH_BASE, bgh, wid, lane, pgh_s);

  // ================= decoder: 513 rounds, ONE barrier per step.
  // Round t: A computes h0^{512+t} (gi from h1^{511+t}, gh prefetched) ->
  // flush -> drain -> publish fA=t+1; then (off critical chain) waits peers
  // and prefetches gh for t+1. B prefetches its gh (h1^{511+t}) during A's
  // phase, waits fA>=t+1, computes h1^{512+t}, flushes. FC emits out_{t-1}
  // from h1^{511+t} with no wait. End-of-round grid barrier.
  for (int t = 0; t <= TT; ++t){
    if (isA && t < TT){
      const int g = 512 + t;
      f32x4 pgi[2];
      if (t == 0)
        gemm<2,64,false>(f0H, f0L, smem, GI0_BASE, bgi0, wid, lane, pgi);
      else
        gemm<2,512,true>(h1rH + SLOT(g-1), h1rL + SLOT(g-1), smem, GI_BASE, bgi, wid, lane, pgi);
      gates_stage(pgi, pgh_s, hold, stH, stL, wid, lane);
      __syncthreads();
      ring_flush(h0rH + SLOT(g) + kblk*512, h0rL + SLOT(g) + kblk*512, stH, stL, tid);
      __syncthreads();                                 // drain flush stores (vmcnt 0)
      if (tid == 0) publish(&fA[wg*16], (uint)(t+1));
      if (t < TT-1){
        waitS(fA, (uint)(t+1), tid);                   // peers' h0^g visible (overlaps B)
        gemm<2,512,true>(h0rH + SLOT(g), h0rL + SLOT(g), smem, GH_BASE, bgh, wid, lane, pgh_s);
      }
    } else if (isB && t < TT){
      const int g = 512 + t;
      f32x4 pgh[2], pgi[2];
      gemm<2,512,true>(h1rH + SLOT(g-1), h1rL + SLOT(g-1), smem, GH_BASE, bgh, wid, lane, pgh);
      waitS(fA, (uint)(t+1), tid);                     // h0^g ready
      gemm<2,512,true>(h0rH + SLOT(g), h0rL + SLOT(g), smem, GI_BASE, bgi, wid, lane, pgi);
      gates_stage(pgi, pgh, hold, stH, stL, wid, lane);
      __syncthreads();
      ring_flush(h1rH + SLOT(g) + kblk*512, h1rL + SLOT(g) + kblk*512, stH, stL, tid);
    } else if (!isA && !isB && t >= 1){
      const int g = 511 + t;                           // h1^g -> out index t-1
      f32x4 pre[1];
      gemm<1,512,true>(h1rH + SLOT(g), h1rL + SLOT(g), smem, 0, &bfc, wid, lane, pre);
      const int outcol = fccol + c, gq = lane >> 4;
#pragma unroll
      for (int q = 0; q < 4; ++q){
        const int row = wid*16 + gq*4 + q;
        p.out[(row*COUT + outcol)*TT + (t-1)] = pre[0][q];
      }
    }
    ++bno;
    gbar(flags, bno, wg, tid, false, (bno & 15u) == 0u);
  }
}

extern "C" void kernel_launch(void* const* d_in, const int* in_sizes, int n_in,
                              void* d_out, int out_size, void* d_ws, size_t ws_size,
                              hipStream_t stream){
  Params p;
  p.x     = (const float*)d_in[0];  p.f0    = (const float*)d_in[1];
  p.eWih0 = (const float*)d_in[2];  p.eWhh0 = (const float*)d_in[3];
  p.ebih0 = (const float*)d_in[4];  p.ebhh0 = (const float*)d_in[5];
  p.eWih1 = (const float*)d_in[6];  p.eWhh1 = (const float*)d_in[7];
  p.ebih1 = (const float*)d_in[8];  p.ebhh1 = (const float*)d_in[9];
  p.dWih0 = (const float*)d_in[10]; p.dWhh0 = (const float*)d_in[11];
  p.dbih0 = (const float*)d_in[12]; p.dbhh0 = (const float*)d_in[13];
  p.dWih1 = (const float*)d_in[14]; p.dWhh1 = (const float*)d_in[15];
  p.dbih1 = (const float*)d_in[16]; p.dbhh1 = (const float*)d_in[17];
  p.fcW   = (const float*)d_in[18]; p.fcb   = (const float*)d_in[19];
  p.out = (float*)d_out;
  p.ws  = (char*)d_ws;

  hipFuncSetAttribute((const void*)rnn_persist, hipFuncAttributeMaxDynamicSharedMemorySize, SMEM_SIZE);
  hipMemsetAsync(d_ws, 0, WS_BAR_SZ, stream);   // reset barrier + dataflow flags each launch
  hipLaunchKernelGGL(rnn_persist, dim3(NWG), dim3(THREADS), SMEM_SIZE, stream, p);
}

// Round 16
// 10284.546 us; speedup vs baseline: 1.1086x; 1.1086x over previous
//
#include <hip/hip_runtime.h>

#define H     512
#define BQ    64
#define TT    512
#define CIN   64
#define COUT  64
#define NWG   132           // 64 stage-A + 64 stage-B + 4 FC
#define THREADS 256
#define RSLOTS 32           // ring slots; address reuse period = 32 steps

typedef unsigned int  uint;
typedef unsigned short ushort;
typedef unsigned long long u64;
typedef short bf16x8 __attribute__((ext_vector_type(8)));
typedef float f32x4  __attribute__((ext_vector_type(4)));

// LDS layout (bytes): gate-interleaved weight pair-tiles, bf16 hi+lo
#define GH_BASE   0          // 2 tiles K=512 : 64 KB
#define GI_BASE   65536      // 2 tiles K<=512: 64 KB
#define GI0_BASE  131072     // 2 tiles K=64  :  8 KB  (dec-A t=0 only)
#define STG_BASE  139264     // ring-store staging: [64][8] hi + lo = 2 KB
#define SMEM_SIZE 141312

// ws layout (bytes). All flag arrays 64B-strided: one writer per line.
#define WS_GF     0          // prepass grid-barrier flags, 132 @64B
#define WS_FA     8448       // fA[64]: A-group absolute step counters
#define WS_FB     12544      // fB[64]
#define WS_FF     16640      // fF[4]
#define WS_BAR_SZ 20480
#define WS_BP     20480      // b' f32[1536]
#define WS_F0H    26624      // f0 hi bf16[64][64] (flat row-major)
#define WS_F0L    34816
#define WS_H0RH   65536      // h0 ring [32 slots][64 kblk][64 row][8 col] bf16 hi : 2 MB
#define WS_H0RL   2162688
#define WS_H1RH   4259840
#define WS_H1RL   6356992
#define WS_M      8454144    // M f32[1536][512]

// slot offset in ushorts for absolute step s
#define SLOT(s)   (((s) & (RSLOTS-1)) * 32768)

struct Params {
  const float *x, *f0;
  const float *eWih0,*eWhh0,*ebih0,*ebhh0,*eWih1,*eWhh1,*ebih1,*ebhh1;
  const float *dWih0,*dWhh0,*dbih0,*dbhh0,*dWih1,*dWhh1,*dbih1,*dbhh1;
  const float *fcW,*fcb;
  float* out;
  char* ws;
};

__device__ __forceinline__ ushort f2bf(float v){
  uint b = __float_as_uint(v);
  return (ushort)((b + 0x7FFFu + ((b >> 16) & 1u)) >> 16);
}
__device__ __forceinline__ float bf2f(ushort u){ return __uint_as_float(((uint)u) << 16); }

// ---------------- dataflow waits: 64 one-writer-per-line flags, relaxed
// coherence-point polls, NO in-loop fences (parachute only). R10/R11 lessons.
__device__ __forceinline__ void waitS(const uint* __restrict__ f, uint thr, int tid){
  if (tid < 64){
    uint it = 0;
    while (__hip_atomic_load(&f[tid*16], __ATOMIC_RELAXED, __HIP_MEMORY_SCOPE_AGENT) < thr){
      __builtin_amdgcn_s_sleep(1);
      if ((++it & 1023u) == 0u) __builtin_amdgcn_fence(__ATOMIC_ACQUIRE, "agent");
    }
  }
  __syncthreads();
}
__device__ __forceinline__ void waitS4(const uint* __restrict__ f, uint thr, int tid){
  if (tid < 4){
    uint it = 0;
    while (__hip_atomic_load(&f[tid*16], __ATOMIC_RELAXED, __HIP_MEMORY_SCOPE_AGENT) < thr){
      __builtin_amdgcn_s_sleep(1);
      if ((++it & 1023u) == 0u) __builtin_amdgcn_fence(__ATOMIC_ACQUIRE, "agent");
    }
  }
  __syncthreads();
}
__device__ __forceinline__ void publish(uint* f, uint v){
  __hip_atomic_store(f, v, __ATOMIC_RELAXED, __HIP_MEMORY_SCOPE_AGENT);
}
// per-WG acquire-inv: cadence 16 own-steps < 32-slot reuse window (R6/R12-validated)
__device__ __forceinline__ void invAll(){
  __builtin_amdgcn_fence(__ATOMIC_ACQUIRE, "agent");
}

// ---------------- prepass grid barrier (once)
__device__ __forceinline__ void gbar(uint* flags, uint r, int wg, int tid){
  __syncthreads();
  if (tid == 0){
    __builtin_amdgcn_fence(__ATOMIC_RELEASE, "agent");   // flush plain-stored staging
    __hip_atomic_store(&flags[wg*16], r, __ATOMIC_RELAXED, __HIP_MEMORY_SCOPE_AGENT);
  }
  asm volatile("" ::: "memory");
  if (tid < NWG){
    uint it = 0;
    while (__hip_atomic_load(&flags[tid*16], __ATOMIC_RELAXED, __HIP_MEMORY_SCOPE_AGENT) < r){
      __builtin_amdgcn_s_sleep(1);
      if ((++it & 1023u) == 0u) __builtin_amdgcn_fence(__ATOMIC_ACQUIRE, "agent");
    }
  }
  __syncthreads();
  __builtin_amdgcn_fence(__ATOMIC_ACQUIRE, "agent");     // start clean
}

// ---------------- pack 2 gate-interleaved pair-tiles (32 slots x K) into LDS
template<int K>
__device__ void packW(char* lds, int base, const float* __restrict__ W, int colbase, int tid){
  for (int e = tid; e < 32*K; e += THREADS){
    int S = e / K, k = e - S*K;
    int gate = S & 3, hcl = S >> 2;
    float v = (gate < 3) ? W[(gate*H + colbase + hcl)*K + k] : 0.f;
    ushort hi = f2bf(v);
    ushort lo = f2bf(v - bf2f(hi));
    int tau = S >> 4, s = S & 15;
    int off = ((s*K + k)*2) ^ ((s & 7) << 4);
    char* tb = lds + base + tau*(16*K*4);
    *(ushort*)(tb + off) = hi;
    *(ushort*)(tb + 16*K*2 + off) = lo;
  }
}

__device__ void packFC(char* lds, const float* __restrict__ fcW, int colbase, int tid){
  for (int e = tid; e < 16*512; e += THREADS){
    int s = e >> 9, k = e & 511;
    float v = fcW[(colbase + s)*512 + k];
    ushort hi = f2bf(v);
    ushort lo = f2bf(v - bf2f(hi));
    int off = ((s*512 + k)*2) ^ ((s & 7) << 4);
    *(ushort*)(lds + off) = hi;
    *(ushort*)(lds + 16*512*2 + off) = lo;
  }
}

__device__ __forceinline__ void loadBias(const float* __restrict__ src, int colbase, int c, float* b){
#pragma unroll
  for (int tau = 0; tau < 2; ++tau){
    int gate = c & 3, hcl = 4*tau + (c >> 2);
    b[tau] = (gate < 3) ? src[gate*H + colbase + hcl] : 0.f;
  }
}

// blocked ring element (row, col): ushort offset (col>>3)*512 + row*8 + (col&7)
__device__ __forceinline__ void loadHold(const ushort* rh, const ushort* rl, int colb,
                                         int m, int lane, f32x4* hold){
  int c = lane & 15, g = lane >> 4;
#pragma unroll
  for (int tau = 0; tau < 2; ++tau){
    int col = colb + 4*tau + (c >> 2);
#pragma unroll
    for (int q = 0; q < 4; ++q){
      int row = m*16 + g*4 + q;
      int off = (col >> 3)*512 + row*8 + (col & 7);
      hold[tau][q] = bf2f(rh[off]) + bf2f(rl[off]);
    }
  }
}

// ---------------- 64xNTAU*16 GEMM tile, split-bf16 3-term, weights from LDS
// BLK=true: A in blocked ring layout [kblk][row][8]. BLK=false: flat [64][K].
template<int NTAU, int K, bool BLK>
__device__ __forceinline__ void gemm(const ushort* __restrict__ AH, const ushort* __restrict__ AL,
                                     const char* lds, int base, const float* bias,
                                     int m, int lane, f32x4* pre){
  const int c = lane & 15, g = lane >> 4;
  const int row = m*16 + c;
  constexpr int NK = K/32;
  bf16x8 ahv[NK], alv[NK];
#pragma unroll
  for (int kc = 0; kc < NK; ++kc){
    const int aoff = BLK ? ((kc*4 + g)*512 + row*8) : (row*K + kc*32 + g*8);
    ahv[kc] = *(const bf16x8*)(AH + aoff);
    alv[kc] = *(const bf16x8*)(AL + aoff);
  }
  f32x4 a1[NTAU], a2[NTAU];
#pragma unroll
  for (int tau = 0; tau < NTAU; ++tau){
    a1[tau] = f32x4{bias[tau], bias[tau], bias[tau], bias[tau]};
    a2[tau] = f32x4{0.f, 0.f, 0.f, 0.f};
  }
#pragma unroll
  for (int kc = 0; kc < NK; ++kc){
    const int off = ((c*K + kc*32 + g*8)*2) ^ ((c & 7) << 4);
#pragma unroll
    for (int tau = 0; tau < NTAU; ++tau){
      const char* tb = lds + base + tau*(16*K*4);
      bf16x8 wh = *(const bf16x8*)(tb + off);
      bf16x8 wl = *(const bf16x8*)(tb + 16*K*2 + off);
      a1[tau] = __builtin_amdgcn_mfma_f32_16x16x32_bf16(ahv[kc], wh, a1[tau], 0, 0, 0);
      a2[tau] = __builtin_amdgcn_mfma_f32_16x16x32_bf16(ahv[kc], wl, a2[tau], 0, 0, 0);
      a2[tau] = __builtin_amdgcn_mfma_f32_16x16x32_bf16(alv[kc], wh, a2[tau], 0, 0, 0);
    }
  }
#pragma unroll
  for (int tau = 0; tau < NTAU; ++tau) pre[tau] = a1[tau] + a2[tau];
}

// ---------------- GRU gates: compute hn, update hold, STAGE hi/lo tiles in LDS.
__device__ __forceinline__ void gates_stage(const f32x4* pgi, const f32x4* pgh, f32x4* hold,
                                            ushort* __restrict__ stH, ushort* __restrict__ stL,
                                            int m, int lane){
  const int c = lane & 15, g = lane >> 4;
#pragma unroll
  for (int tau = 0; tau < 2; ++tau){
    f32x4 s, n, hn, rsh, zsh;
#pragma unroll
    for (int q = 0; q < 4; ++q) s[q] = 1.f / (1.f + expf(-(pgi[tau][q] + pgh[tau][q])));
#pragma unroll
    for (int q = 0; q < 4; ++q) rsh[q] = __shfl_xor(s[q], 2, 64);
#pragma unroll
    for (int q = 0; q < 4; ++q) zsh[q] = __shfl_xor(s[q], 3, 64);
#pragma unroll
    for (int q = 0; q < 4; ++q) n[q] = tanhf(pgi[tau][q] + rsh[q]*pgh[tau][q]);
#pragma unroll
    for (int q = 0; q < 4; ++q) hn[q] = (1.f - zsh[q])*n[q] + zsh[q]*hold[tau][q];
    hold[tau] = hn;
    if ((c & 3) == 2){
      const int cl = 4*tau + (c >> 2);                // local col 0..7
#pragma unroll
      for (int q = 0; q < 4; ++q){
        const int row = m*16 + g*4 + q;
        ushort hi = f2bf(hn[q]);
        ushort lo = f2bf(hn[q] - bf2f(hi));
        stH[row*8 + cl] = hi;
        stL[row*8 + cl] = lo;
      }
    }
  }
}

// ---------------- flush staged [64][8] tiles as 32 FULL 64B lines per WG
__device__ __forceinline__ void ring_flush(ushort* __restrict__ dH, ushort* __restrict__ dL,
                                           const ushort* __restrict__ stH,
                                           const ushort* __restrict__ stL, int tid){
  if (tid < 128){
    u64 v = *(const u64*)(stH + tid*4);
    __hip_atomic_store((u64*)dH + tid, v, __ATOMIC_RELAXED, __HIP_MEMORY_SCOPE_AGENT);
  } else if (tid < 256){
    int t2 = tid - 128;
    u64 v = *(const u64*)(stL + t2*4);
    __hip_atomic_store((u64*)dL + t2, v, __ATOMIC_RELAXED, __HIP_MEMORY_SCOPE_AGENT);
  }
}

__device__ __forceinline__ f32x4 bc4(float v){ return f32x4{v, v, v, v}; }

__global__ __launch_bounds__(THREADS, 1) void rnn_persist(Params p){
  extern __shared__ char smem[];
  char* ws = p.ws;
  uint* gflags = (uint*)(ws + WS_GF);
  uint* fA     = (uint*)(ws + WS_FA);
  uint* fB     = (uint*)(ws + WS_FB);
  uint* fF     = (uint*)(ws + WS_FF);
  float*  bp   = (float*)(ws + WS_BP);
  ushort* f0H  = (ushort*)(ws + WS_F0H);
  ushort* f0L  = (ushort*)(ws + WS_F0L);
  ushort* h0rH = (ushort*)(ws + WS_H0RH);
  ushort* h0rL = (ushort*)(ws + WS_H0RL);
  ushort* h1rH = (ushort*)(ws + WS_H1RH);
  ushort* h1rL = (ushort*)(ws + WS_H1RL);
  float*  Mw   = (float*)(ws + WS_M);
  ushort* xTH  = (ushort*)(void*)p.out;              // staged in d_out; all xT reads complete
  ushort* xTL  = xTH + TT*BQ*CIN;                    //  before any FC write (fA>=513 chain)
  ushort* stH  = (ushort*)(smem + STG_BASE);         // [64][8] staging
  ushort* stL  = stH + 512;

  const int wg = blockIdx.x, tid = threadIdx.x;
  const int wid = tid >> 6, lane = tid & 63;
  const int c = lane & 15;
  const int gtid = wg*THREADS + tid;
  const int gstride = NWG*THREADS;

  // ================= prepass: xT (transpose+split), f0, M = dWih0@fcW, b'
  for (int e = gtid; e < TT*BQ*CIN; e += gstride){
    int t = e >> 12, b = (e >> 6) & 63, cc = e & 63;
    float v = p.x[(b*CIN + cc)*TT + t];
    ushort hi = f2bf(v);
    xTH[e] = hi; xTL[e] = f2bf(v - bf2f(hi));
  }
  for (int e = gtid; e < BQ*COUT; e += gstride){
    float v = p.f0[e];
    ushort hi = f2bf(v);
    f0H[e] = hi; f0L[e] = f2bf(v - bf2f(hi));
  }
  {
    const int total = 1536*512;
    const int per = (total + gstride - 1) / gstride;
    const int start = gtid * per;
    for (int i = 0; i < per; ++i){
      int e = start + i;
      if (e >= total) break;
      int rr = e >> 9, q = e & 511;
      float acc = 0.f;
      for (int k = 0; k < 64; ++k) acc += p.dWih0[rr*64 + k] * p.fcW[k*512 + q];
      Mw[e] = acc;
    }
  }
  for (int e = gtid; e < 1536; e += gstride){
    float acc = p.dbih0[e];
    for (int k = 0; k < 64; ++k) acc += p.dWih0[e*64 + k] * p.fcb[k];
    bp[e] = acc;
  }
  gbar(gflags, 1, wg, tid);   // the ONLY grid barrier

  const bool isA = (wg < 64), isB = (wg >= 64 && wg < 128);
  const int colb = isA ? wg*8 : (wg - 64)*8;
  const int kblk = colb >> 3;
  float bgi[2] = {0.f,0.f}, bgh[2] = {0.f,0.f}, bgi0[2] = {0.f,0.f}, bfc = 0.f;
  f32x4 hold[2]; hold[0] = bc4(0.f); hold[1] = bc4(0.f);

  if (isA){
    // ======== encoder L0 (free-running; B trails via flags)
    packW<64 >(smem, GI_BASE, p.eWih0, colb, tid);
    packW<512>(smem, GH_BASE, p.eWhh0, colb, tid);
    loadBias(p.ebih0, colb, c, bgi); loadBias(p.ebhh0, colb, c, bgh);
    __syncthreads();
    for (int t = 0; t < TT; ++t){
      if ((t & 15) == 0 && t > 0) invAll();
      f32x4 pgi[2], pgh[2];
      if (t > 0){
        waitS(fA, (uint)t, tid);                               // peers' h0^{t-1}
        gemm<2,512,true>(h0rH + SLOT(t-1), h0rL + SLOT(t-1), smem, GH_BASE, bgh, wid, lane, pgh);
      } else { pgh[0] = bc4(bgh[0]); pgh[1] = bc4(bgh[1]); }
      gemm<2,64,false>(xTH + t*4096, xTL + t*4096, smem, GI_BASE, bgi, wid, lane, pgi);
      if (t >= 32 && (t & 15) == 0) waitS(fB, (uint)(t-16), tid);  // overwrite guard
      gates_stage(pgi, pgh, hold, stH, stL, wid, lane);
      __syncthreads();
      ring_flush(h0rH + SLOT(t) + kblk*512, h0rL + SLOT(t) + kblk*512, stH, stL, tid);
      __syncthreads();                                         // drain flush stores
      if (tid == 0) publish(&fA[wg*16], (uint)(t+1));
    }
    // ======== repack for decoder L0
    __syncthreads();
    packW<512>(smem, GH_BASE, p.dWhh0, colb, tid);
    packW<512>(smem, GI_BASE, Mw,      colb, tid);             // folded FC->L0 weights
    packW<64 >(smem, GI0_BASE, p.dWih0, colb, tid);
    loadBias(bp,      colb, c, bgi);
    loadBias(p.dbhh0, colb, c, bgh);
    loadBias(p.dbih0, colb, c, bgi0);
    __syncthreads();
    waitS(fA, (uint)TT, tid);                                  // all A peers done
    invAll();
    loadHold(h0rH + SLOT(511), h0rL + SLOT(511), colb, wid, lane, hold);
    // ======== decoder L0: h0^{512+t}
    for (int t = 0; t < TT; ++t){
      const int g = 512 + t;
      if ((t & 15) == 0 && t > 0) invAll();
      f32x4 pgi[2], pgh[2];
      waitS(fA, (uint)g, tid);                                 // peers' h0^{g-1}
      gemm<2,512,true>(h0rH + SLOT(g-1), h0rL + SLOT(g-1), smem, GH_BASE, bgh, wid, lane, pgh);
      if (t == 0){
        waitS(fB, 481u, tid);                                  // slot-0 overwrite guard
        gemm<2,64,false>(f0H, f0L, smem, GI0_BASE, bgi0, wid, lane, pgi);
      } else {
        waitS(fB, (uint)g, tid);                               // h1^{g-1} (covers guards)
        gemm<2,512,true>(h1rH + SLOT(g-1), h1rL + SLOT(g-1), smem, GI_BASE, bgi, wid, lane, pgi);
      }
      gates_stage(pgi, pgh, hold, stH, stL, wid, lane);
      __syncthreads();
      ring_flush(h0rH + SLOT(g) + kblk*512, h0rL + SLOT(g) + kblk*512, stH, stL, tid);
      __syncthreads();
      if (tid == 0) publish(&fA[wg*16], (uint)(g+1));
    }
  } else if (isB){
    // ======== encoder L1 (consumes A's ring)
    packW<512>(smem, GI_BASE, p.eWih1, colb, tid);
    packW<512>(smem, GH_BASE, p.eWhh1, colb, tid);
    loadBias(p.ebih1, colb, c, bgi); loadBias(p.ebhh1, colb, c, bgh);
    __syncthreads();
    for (int t = 0; t < TT; ++t){
      if ((t & 15) == 0 && t > 0) invAll();
      f32x4 pgi[2], pgh[2];
      if (t > 0){
        waitS(fB, (uint)t, tid);                               // peers' h1^{t-1}
        gemm<2,512,true>(h1rH + SLOT(t-1), h1rL + SLOT(t-1), smem, GH_BASE, bgh, wid, lane, pgh);
      } else { pgh[0] = bc4(bgh[0]); pgh[1] = bc4(bgh[1]); }
      waitS(fA, (uint)(t+1), tid);                             // h0^t ready
      gemm<2,512,true>(h0rH + SLOT(t), h0rL + SLOT(t), smem, GI_BASE, bgi, wid, lane, pgi);
      gates_stage(pgi, pgh, hold, stH, stL, wid, lane);
      __syncthreads();
      ring_flush(h1rH + SLOT(t) + kblk*512, h1rL + SLOT(t) + kblk*512, stH, stL, tid);
      __syncthreads();
      if (tid == 0) publish(&fB[wg*16 - 64*16], (uint)(t+1));
    }
    // ======== repack for decoder L1
    __syncthreads();
    packW<512>(smem, GI_BASE, p.dWih1, colb, tid);
    packW<512>(smem, GH_BASE, p.dWhh1, colb, tid);
    loadBias(p.dbih1, colb, c, bgi); loadBias(p.dbhh1, colb, c, bgh);
    __syncthreads();
    waitS(fB, (uint)TT, tid);                                  // all B peers done
    invAll();
    loadHold(h1rH + SLOT(511), h1rL + SLOT(511), colb, wid, lane, hold);
    // ======== decoder L1: h1^{512+t}
    for (int t = 0; t < TT; ++t){
      const int g = 512 + t;
      if ((t & 15) == 0 && t > 0) invAll();
      f32x4 pgi[2], pgh[2];
      waitS(fB, (uint)g, tid);                                 // peers' h1^{g-1}
      gemm<2,512,true>(h1rH + SLOT(g-1), h1rL + SLOT(g-1), smem, GH_BASE, bgh, wid, lane, pgh);
      if (t >= 32 && (t & 15) == 0) waitS4(fF, (uint)(t-16), tid);  // FC-consumed guard
      waitS(fA, (uint)(g+1), tid);                             // h0^g ready
      gemm<2,512,true>(h0rH + SLOT(g), h0rL + SLOT(g), smem, GI_BASE, bgi, wid, lane, pgi);
      gates_stage(pgi, pgh, hold, stH, stL, wid, lane);
      __syncthreads();
      ring_flush(h1rH + SLOT(g) + kblk*512, h1rL + SLOT(g) + kblk*512, stH, stL, tid);
      __syncthreads();
      if (tid == 0) publish(&fB[wg*16 - 64*16], (uint)(g+1));
    }
  } else {
    // ======== FC head: trails B by one handoff
    const int fccol = (wg - 128)*16;
    packFC(smem, p.fcW, fccol, tid);
    bfc = p.fcb[fccol + c];
    __syncthreads();
    for (int t = 0; t < TT; ++t){
      const int g = 512 + t;
      if ((t & 15) == 0) invAll();
      waitS(fB, (uint)(g+1), tid);                             // h1^g ready
      f32x4 pre[1];
      gemm<1,512,true>(h1rH + SLOT(g), h1rL + SLOT(g), smem, 0, &bfc, wid, lane, pre);
      const int outcol = fccol + c, gq = lane >> 4;
#pragma unroll
      for (int q = 0; q < 4; ++q){
        const int row = wid*16 + gq*4 + q;
        p.out[(row*COUT + outcol)*TT + t] = pre[0][q];
      }
      __syncthreads();                                         // reads of slot complete
      if (tid == 0) publish(&fF[(wg-128)*16], (uint)(t+1));
    }
  }
}

extern "C" void kernel_launch(void* const* d_in, const int* in_sizes, int n_in,
                              void* d_out, int out_size, void* d_ws, size_t ws_size,
                              hipStream_t stream){
  Params p;
  p.x     = (const float*)d_in[0];  p.f0    = (const float*)d_in[1];
  p.eWih0 = (const float*)d_in[2];  p.eWhh0 = (const float*)d_in[3];
  p.ebih0 = (const float*)d_in[4];  p.ebhh0 = (const float*)d_in[5];
  p.eWih1 = (const float*)d_in[6];  p.eWhh1 = (const float*)d_in[7];
  p.ebih1 = (const float*)d_in[8];  p.ebhh1 = (const float*)d_in[9];
  p.dWih0 = (const float*)d_in[10]; p.dWhh0 = (const float*)d_in[11];
  p.dbih0 = (const float*)d_in[12]; p.dbhh0 = (const float*)d_in[13];
  p.dWih1 = (const float*)d_in[14]; p.dWhh1 = (const float*)d_in[15];
  p.dbih1 = (const float*)d_in[16]; p.dbhh1 = (const float*)d_in[17];
  p.fcW   = (const float*)d_in[18]; p.fcb   = (const float*)d_in[19];
  p.out = (float*)d_out;
  p.ws  = (char*)d_ws;

  hipFuncSetAttribute((const void*)rnn_persist, hipFuncAttributeMaxDynamicSharedMemorySize, SMEM_SIZE);
  hipMemsetAsync(d_ws, 0, WS_BAR_SZ, stream);   // reset all flags each launch
  hipLaunchKernelGGL(rnn_persist, dim3(NWG), dim3(THREADS), SMEM_SIZE, stream, p);
}